// Round 10
// baseline (402.539 us; speedup 1.0000x reference)
//
#include <hip/hip_runtime.h>
#include <hip/hip_bf16.h>

#define S_LEN 4096
#define D_MODEL 1024
#define NH 16
#define DHEAD 64
#define LP 72   // padded LDS row stride for attn tiles: 144B, 16B-aligned
// Q pre-scale: 1/sqrt(D) * log2(e)  (exp(x/32) == exp2(x*log2e/32))
#define QSCALE 0.0450843293f

typedef __attribute__((ext_vector_type(8))) short short8;
typedef __attribute__((ext_vector_type(4))) short short4v;
typedef __attribute__((ext_vector_type(4))) float floatx4;

__device__ __forceinline__ unsigned short f2bf(float f) {
    unsigned int x = __float_as_uint(f);
    x += 0x7fffu + ((x >> 16) & 1u);
    return (unsigned short)(x >> 16);
}

// 2^x via v_exp_f32 (avoid __exp2f: glibc math.h macro collision)
__device__ __forceinline__ float exp2_fast(float x) {
    return __builtin_amdgcn_exp2f(x);
}

// async global->LDS, 16B per lane, dest = wave-uniform base + lane*16
__device__ __forceinline__ void async_copy16(const unsigned short* g, unsigned short* l) {
    __builtin_amdgcn_global_load_lds(
        (const __attribute__((address_space(1))) void*)g,
        (__attribute__((address_space(3))) void*)l, 16, 0, 0);
}

// ---------------------------------------------------------------------------
// prep_all: merged input cast + weight transpose (one launch).
// ---------------------------------------------------------------------------
__global__ __launch_bounds__(256) void prep_all(
    const float* __restrict__ q, const float* __restrict__ k,
    const float* __restrict__ v,
    const float* __restrict__ Wq, const float* __restrict__ Wk,
    const float* __restrict__ Wv, const float* __restrict__ Wo,
    unsigned short* __restrict__ ws, unsigned short* __restrict__ qkvb)
{
    __shared__ float L[64][65];
    const int bx0 = blockIdx.x;
    const int tid = threadIdx.x;

    if (bx0 < 6144) {
        long i = (long)(bx0 * 256 + tid) * 8;
        int which = (int)(i >> 22);
        long off = i & ((1 << 22) - 1);
        const float* src = (which == 0) ? q : (which == 1) ? k : v;
        float4 f0 = *(const float4*)&src[off];
        float4 f1 = *(const float4*)&src[off + 4];
        uint4 o;
        o.x = (unsigned int)f2bf(f0.x) | ((unsigned int)f2bf(f0.y) << 16);
        o.y = (unsigned int)f2bf(f0.z) | ((unsigned int)f2bf(f0.w) << 16);
        o.z = (unsigned int)f2bf(f1.x) | ((unsigned int)f2bf(f1.y) << 16);
        o.w = (unsigned int)f2bf(f1.z) | ((unsigned int)f2bf(f1.w) << 16);
        *(uint4*)&qkvb[i] = o;
        return;
    }

    const int bx  = bx0 - 6144;
    const int mat = bx >> 8;
    if (mat < 3) {
        const float* W = (mat == 0) ? Wq : (mat == 1) ? Wk : Wv;
        unsigned short* WT = ws + (size_t)mat * (1u << 20);
        int h  = (bx >> 4) & 15;
        int dt = bx & 15;
        #pragma unroll
        for (int i = 0; i < 16; i++) {
            int idx = i * 256 + tid;
            int dp = idx >> 6, e = idx & 63;
            L[e][dp] = W[h * 65536 + (dt * 64 + dp) * 64 + e];
        }
        __syncthreads();
        #pragma unroll
        for (int i = 0; i < 16; i++) {
            int idx = i * 256 + tid;
            int e = idx >> 6, dp = idx & 63;
            WT[(h * 64 + e) * 1024 + dt * 64 + dp] = f2bf(L[e][dp]);
        }
    } else {
        unsigned short* WoT = ws + (size_t)3 * (1u << 20);
        int rt = (bx >> 4) & 15;
        int ct = bx & 15;
        #pragma unroll
        for (int i = 0; i < 16; i++) {
            int idx = i * 256 + tid;
            int dp = idx >> 6, np = idx & 63;
            L[np][dp] = Wo[(rt * 64 + dp) * 1024 + ct * 64 + np];
        }
        __syncthreads();
        #pragma unroll
        for (int i = 0; i < 16; i++) {
            int idx = i * 256 + tid;
            int np = idx >> 6, dp = idx & 63;
            WoT[(ct * 64 + np) * 1024 + rt * 64 + dp] = f2bf(L[np][dp]);
        }
    }
}

// ---------------------------------------------------------------------------
// 128x128 GEMM core (m97 structure): BK=64, global_load_lds staging,
// unpadded LDS (DMA lane-order), 4 waves in 2x2, 4x4 16x16x32 accs each.
// ---------------------------------------------------------------------------
#define GEMM_CORE(XPTR, WPTR)                                                   \
    for (int k0 = 0; k0 < D_MODEL; k0 += 64) {                                  \
        __syncthreads();                                                        \
        _Pragma("unroll")                                                       \
        for (int i = 0; i < 4; i++) {                                           \
            async_copy16(&XPTR[(size_t)(m0 + srow + i * 8) * D_MODEL + k0 + scol], \
                         &As[(wave * 32 + i * 8) * 64]);                        \
            async_copy16(&WPTR[(size_t)(n0 + srow + i * 8) * D_MODEL + k0 + scol], \
                         &Bs[(wave * 32 + i * 8) * 64]);                        \
        }                                                                       \
        __syncthreads();                                                        \
        _Pragma("unroll")                                                       \
        for (int ks = 0; ks < 2; ks++) {                                        \
            short8 af[4], bf[4];                                                \
            _Pragma("unroll")                                                   \
            for (int i = 0; i < 4; i++)                                         \
                af[i] = *(const short8*)&As[(wr * 64 + i * 16 + m) * 64 + ks * 32 + quad * 8]; \
            _Pragma("unroll")                                                   \
            for (int j = 0; j < 4; j++)                                         \
                bf[j] = *(const short8*)&Bs[(wc * 64 + j * 16 + m) * 64 + ks * 32 + quad * 8]; \
            _Pragma("unroll")                                                   \
            for (int i = 0; i < 4; i++) {                                       \
                _Pragma("unroll")                                               \
                for (int j = 0; j < 4; j++)                                     \
                    acc[i][j] = __builtin_amdgcn_mfma_f32_16x16x32_bf16(af[i], bf[j], acc[i][j], 0, 0, 0); \
            }                                                                   \
        }                                                                       \
    }

// qkv_gemm: z=0 -> Q[h][s][e] scaled by QSCALE; z=1 -> K[h][s][e]; z=2 -> V^T[h][e][s]
__global__ __launch_bounds__(256) void qkv_gemm(
    const unsigned short* __restrict__ Xbase, const unsigned short* __restrict__ WTbase,
    const float* __restrict__ bq, const float* __restrict__ bk,
    const float* __restrict__ bv,
    unsigned short* __restrict__ Qbuf, unsigned short* __restrict__ Kbuf,
    unsigned short* __restrict__ Vbuf)
{
    __shared__ __align__(16) unsigned short As[128 * 64];
    __shared__ __align__(16) unsigned short Bs[128 * 64];

    const int z = blockIdx.z;
    const unsigned short* X  = Xbase + (size_t)z * (4u << 20);
    const unsigned short* WT = WTbase + (size_t)z * (1u << 20);
    const float* bias = (z == 0) ? bq : (z == 1) ? bk : bv;

    const int n0 = blockIdx.x * 128;
    const int m0 = blockIdx.y * 128;
    const int tid = threadIdx.x, wave = tid >> 6, lane = tid & 63;
    const int m = lane & 15, quad = lane >> 4;
    const int wr = wave >> 1, wc = wave & 1;
    const int srow = wave * 32 + (lane >> 3);
    const int scol = (lane & 7) * 8;

    floatx4 acc[4][4];
    #pragma unroll
    for (int i = 0; i < 4; i++)
        #pragma unroll
        for (int j = 0; j < 4; j++) acc[i][j] = (floatx4){0.f, 0.f, 0.f, 0.f};

    GEMM_CORE(X, WT)

    #pragma unroll
    for (int j = 0; j < 4; j++) {
        int n = n0 + wc * 64 + j * 16 + m;
        int h = n >> 6, e = n & 63;
        float bvv = bias[n];
        #pragma unroll
        for (int i = 0; i < 4; i++) {
            int sbase = m0 + wr * 64 + i * 16 + quad * 4;
            if (z == 2) {
                ushort4 pk;
                pk.x = f2bf(acc[i][j][0] + bvv);
                pk.y = f2bf(acc[i][j][1] + bvv);
                pk.z = f2bf(acc[i][j][2] + bvv);
                pk.w = f2bf(acc[i][j][3] + bvv);
                *(ushort4*)&Vbuf[h * (DHEAD * S_LEN) + e * S_LEN + sbase] = pk;
            } else if (z == 1) {
                #pragma unroll
                for (int r = 0; r < 4; r++)
                    Kbuf[h * (S_LEN * DHEAD) + (sbase + r) * DHEAD + e] = f2bf(acc[i][j][r] + bvv);
            } else {
                #pragma unroll
                for (int r = 0; r < 4; r++)
                    Qbuf[h * (S_LEN * DHEAD) + (sbase + r) * DHEAD + e] =
                        f2bf((acc[i][j][r] + bvv) * QSCALE);
            }
        }
    }
}

// ---------------------------------------------------------------------------
// out_gemm: 64m x 128n tile, grid (8,64) = 512 blocks. fp32 output [s][n].
// ---------------------------------------------------------------------------
__global__ __launch_bounds__(256) void out_gemm(
    const unsigned short* __restrict__ Cbuf, const unsigned short* __restrict__ WoT,
    const float* __restrict__ bo, float* __restrict__ out)
{
    __shared__ __align__(16) unsigned short As[64 * 64];
    __shared__ __align__(16) unsigned short Bs[128 * 64];

    const int n0 = blockIdx.x * 128;
    const int m0 = blockIdx.y * 64;
    const int tid = threadIdx.x, wave = tid >> 6, lane = tid & 63;
    const int m = lane & 15, quad = lane >> 4;
    const int wr = wave >> 1, wc = wave & 1;
    const int srowA = wave * 16 + (lane >> 3);
    const int srowB = wave * 32 + (lane >> 3);
    const int scol  = (lane & 7) * 8;

    floatx4 acc[2][4];
    #pragma unroll
    for (int i = 0; i < 2; i++)
        #pragma unroll
        for (int j = 0; j < 4; j++) acc[i][j] = (floatx4){0.f, 0.f, 0.f, 0.f};

    for (int k0 = 0; k0 < D_MODEL; k0 += 64) {
        __syncthreads();
        #pragma unroll
        for (int i = 0; i < 2; i++)
            async_copy16(&Cbuf[(size_t)(m0 + srowA + i * 8) * D_MODEL + k0 + scol],
                         &As[(wave * 16 + i * 8) * 64]);
        #pragma unroll
        for (int i = 0; i < 4; i++)
            async_copy16(&WoT[(size_t)(n0 + srowB + i * 8) * D_MODEL + k0 + scol],
                         &Bs[(wave * 32 + i * 8) * 64]);
        __syncthreads();
        #pragma unroll
        for (int ks = 0; ks < 2; ks++) {
            short8 af[2], bf[4];
            #pragma unroll
            for (int i = 0; i < 2; i++)
                af[i] = *(const short8*)&As[(wr * 32 + i * 16 + m) * 64 + ks * 32 + quad * 8];
            #pragma unroll
            for (int j = 0; j < 4; j++)
                bf[j] = *(const short8*)&Bs[(wc * 64 + j * 16 + m) * 64 + ks * 32 + quad * 8];
            #pragma unroll
            for (int i = 0; i < 2; i++)
                #pragma unroll
                for (int j = 0; j < 4; j++)
                    acc[i][j] = __builtin_amdgcn_mfma_f32_16x16x32_bf16(af[i], bf[j], acc[i][j], 0, 0, 0);
        }
    }

    #pragma unroll
    for (int j = 0; j < 4; j++) {
        int n = n0 + wc * 64 + j * 16 + m;
        float bvv = bo[n];
        #pragma unroll
        for (int i = 0; i < 2; i++) {
            int sbase = m0 + wr * 32 + i * 16 + quad * 4;
            #pragma unroll
            for (int r = 0; r < 4; r++)
                out[(size_t)(sbase + r) * D_MODEL + n] = acc[i][j][r] + bvv;
        }
    }
}

// ---------------------------------------------------------------------------
// Flash attention v6: register-resident P (no LDS round-trip, no barrier C).
// Identity: 16x16 MFMA C-layout (col=lane&15=q, row=quad*4+r=t) IS the
// A-layout of v_mfma_f32_16x16x16_bf16 (m=lane&15, k=quad*4+j). So wave w
// computes S^T for its 16 t-rows (A=K frags, B=16 reg Q frags), exps in
// place, packs to bf16, and feeds PV DIRECTLY as A with V b64 B-frags
// (B[n=e][k=t]); each wave accumulates a t-partial O[64q][64e] (64 VGPRs),
// reduced across waves once per block via a 2-chunk fp32 LDS epilogue.
// Per block-iter LDS reads: 16 KB (K once, V once) vs v3's 48 KB.
// ---------------------------------------------------------------------------
__global__ __launch_bounds__(256) void attn_kernel(
    const unsigned short* __restrict__ Q, const unsigned short* __restrict__ K,
    const unsigned short* __restrict__ VT, unsigned short* __restrict__ concat)
{
    // smem union: loop = Ks[64][LP] + Vs[64][LP] (18432 B);
    // epilogue = fp32 Rb[128 erows][68] (34816 B). Ls separate.
    __shared__ __align__(16) unsigned char smem[34816];
    __shared__ float Ls[4][64];
    unsigned short (*Ks)[LP] = (unsigned short(*)[LP])smem;
    unsigned short (*Vs)[LP] = (unsigned short(*)[LP])(smem + 9216);
    float* Rb = (float*)smem;

    const int h  = blockIdx.y;
    const int q0 = blockIdx.x * 64;
    const unsigned short* Qh = Q  + h * (S_LEN * DHEAD);
    const unsigned short* Kh = K  + h * (S_LEN * DHEAD);
    const unsigned short* Vh = VT + h * (DHEAD * S_LEN);

    const int tid  = threadIdx.x;
    const int wave = tid >> 6;
    const int lane = tid & 63;
    const int m    = lane & 15;
    const int quad = lane >> 4;

    // stage Q (pre-scaled) via Ks region; cache 8 B-frags (16x16x32 layout)
    #pragma unroll
    for (int c = tid; c < 512; c += 256) {
        int r = c >> 3, col = (c & 7) << 3;
        *(uint4*)&Ks[r][col] = *(const uint4*)&Qh[(q0 + r) * DHEAD + col];
    }
    __syncthreads();
    short8 bq[4][2];
    #pragma unroll
    for (int qc = 0; qc < 4; qc++)
        #pragma unroll
        for (int ks = 0; ks < 2; ks++)
            bq[qc][ks] = *(const short8*)&Ks[qc * 16 + m][ks * 32 + quad * 8];

    floatx4 O[4][4];   // [qc][nb]: O[q=qc*16+quad*4+r][e=nb*16+m], t-partial
    #pragma unroll
    for (int qc = 0; qc < 4; qc++)
        #pragma unroll
        for (int nb = 0; nb < 4; nb++) O[qc][nb] = (floatx4){0.f, 0.f, 0.f, 0.f};
    float lsum[4] = {0.f, 0.f, 0.f, 0.f};

    for (int t0 = 0; t0 < S_LEN; t0 += 64) {
        __syncthreads();   // A: prev iter's K/V frag reads done
        #pragma unroll
        for (int c = tid; c < 1024; c += 256) {
            int r = c >> 3, col = (c & 7) << 3;
            if (c < 512) {
                *(uint4*)&Ks[r][col] = *(const uint4*)&Kh[(t0 + r) * DHEAD + col];
            } else {
                int e = r - 64;
                *(uint4*)&Vs[e][col] = *(const uint4*)&Vh[e * S_LEN + t0 + col];
            }
        }
        __syncthreads();   // B: staging complete

        // K A-frags (wave's 16 t-rows) + V B-frags (b64: [n=e][k=t in wave's slice])
        short8 ak0 = *(const short8*)&Ks[wave * 16 + m][quad * 8];
        short8 ak1 = *(const short8*)&Ks[wave * 16 + m][32 + quad * 8];
        short4v vb[4];
        #pragma unroll
        for (int nb = 0; nb < 4; nb++)
            vb[nb] = *(const short4v*)&Vs[nb * 16 + m][wave * 16 + quad * 4];

        #pragma unroll
        for (int qc = 0; qc < 4; qc++) {
            // S^T tile: wave's 16 t x 16 q (C: col=q, row=t-local)
            floatx4 st = (floatx4){0.f, 0.f, 0.f, 0.f};
            st = __builtin_amdgcn_mfma_f32_16x16x32_bf16(ak0, bq[qc][0], st, 0, 0, 0);
            st = __builtin_amdgcn_mfma_f32_16x16x32_bf16(ak1, bq[qc][1], st, 0, 0, 0);

            // P = exp2(S'); C-layout == A-layout of 16x16x16 -> no LDS
            float p0 = exp2_fast(st[0]);
            float p1 = exp2_fast(st[1]);
            float p2 = exp2_fast(st[2]);
            float p3 = exp2_fast(st[3]);
            lsum[qc] += (p0 + p1) + (p2 + p3);
            union { unsigned int u[2]; short4v s; } pk;
            pk.u[0] = __builtin_amdgcn_perm(__float_as_uint(p1) + 0x8000u,
                                            __float_as_uint(p0) + 0x8000u, 0x07060302u);
            pk.u[1] = __builtin_amdgcn_perm(__float_as_uint(p3) + 0x8000u,
                                            __float_as_uint(p2) + 0x8000u, 0x07060302u);

            // PV partial over wave's 16 t: O[qc][nb] += P * V
            #pragma unroll
            for (int nb = 0; nb < 4; nb++)
                O[qc][nb] = __builtin_amdgcn_mfma_f32_16x16x16bf16_1k(pk.s, vb[nb], O[qc][nb], 0, 0, 0);
        }
    }

    // lsum[qc]: q = qc*16+m partial over wave's t-slice; reduce quads now
    #pragma unroll
    for (int qc = 0; qc < 4; qc++) {
        lsum[qc] += __shfl_xor(lsum[qc], 16);
        lsum[qc] += __shfl_xor(lsum[qc], 32);
    }
    if (quad == 0) {
        #pragma unroll
        for (int qc = 0; qc < 4; qc++) Ls[wave][qc * 16 + m] = lsum[qc];
    }

    // Epilogue: cross-wave O reduction, 2 chunks of 32 e, fp32 in smem.
    const int qo = tid >> 2;        // q this thread finalizes
    const int eo = tid & 3;         // e-slot (8 e each within chunk)
    for (int cc = 0; cc < 2; cc++) {
        __syncthreads();            // (cc=0: also publishes Ls, ends loop reads)
        #pragma unroll
        for (int qc = 0; qc < 4; qc++)
            #pragma unroll
            for (int nbl = 0; nbl < 2; nbl++) {
                int erow = wave * 32 + nbl * 16 + m;
                *(floatx4*)&Rb[erow * 68 + qc * 16 + quad * 4] = O[qc][cc * 2 + nbl];
            }
        __syncthreads();
        float linv = 1.0f / (Ls[0][qo] + Ls[1][qo] + Ls[2][qo] + Ls[3][qo]);
        #pragma unroll
        for (int e8 = 0; e8 < 8; e8 += 2) {
            int el = eo * 8 + e8;
            float s0 = Rb[(0 * 32 + el) * 68 + qo] + Rb[(1 * 32 + el) * 68 + qo]
                     + Rb[(2 * 32 + el) * 68 + qo] + Rb[(3 * 32 + el) * 68 + qo];
            int el1 = el + 1;
            float s1 = Rb[(0 * 32 + el1) * 68 + qo] + Rb[(1 * 32 + el1) * 68 + qo]
                     + Rb[(2 * 32 + el1) * 68 + qo] + Rb[(3 * 32 + el1) * 68 + qo];
            unsigned int d = (unsigned int)f2bf(s0 * linv)
                           | ((unsigned int)f2bf(s1 * linv) << 16);
            *(unsigned int*)&concat[(size_t)(q0 + qo) * D_MODEL + h * DHEAD + cc * 32 + el] = d;
        }
    }
}

// ---------------------------------------------------------------------------
// ws layout (bf16 elems): WqT@0 WkT@1M WvT@2M WoT@3M | Qbuf@4M Kbuf@8M
// Vbuf@12M Cbuf@16M | qkvb@20M (12M scratch)  => 32M elems = 64MB.
// ---------------------------------------------------------------------------
extern "C" void kernel_launch(void* const* d_in, const int* in_sizes, int n_in,
                              void* d_out, int out_size, void* d_ws, size_t ws_size,
                              hipStream_t stream) {
    const float* q  = (const float*)d_in[0];
    const float* k  = (const float*)d_in[1];
    const float* v  = (const float*)d_in[2];
    const float* Wq = (const float*)d_in[3];
    const float* bq = (const float*)d_in[4];
    const float* Wk = (const float*)d_in[5];
    const float* bk = (const float*)d_in[6];
    const float* Wv = (const float*)d_in[7];
    const float* bv = (const float*)d_in[8];
    const float* Wo = (const float*)d_in[9];
    const float* bo = (const float*)d_in[10];
    float* out = (float*)d_out;

    unsigned short* ws = (unsigned short*)d_ws;
    const size_t M1 = 1u << 20;
    unsigned short* WqT  = ws;
    unsigned short* WoT  = ws + 3 * M1;
    unsigned short* Qbuf = ws + 4 * M1;    // [H][S][64], pre-scaled by QSCALE
    unsigned short* Kbuf = ws + 8 * M1;    // [H][S][64]
    unsigned short* Vbuf = ws + 12 * M1;   // [H][64][S]
    unsigned short* Cbuf = ws + 16 * M1;   // [S][1024]
    unsigned short* qkvb = ws + 20 * M1;   // bf16 q,k,v contiguous

    prep_all<<<7168, 256, 0, stream>>>(q, k, v, Wq, Wk, Wv, Wo, ws, qkvb);

    dim3 gq(8, 32, 3);
    qkv_gemm<<<gq, 256, 0, stream>>>(qkvb, WqT, bq, bk, bv, Qbuf, Kbuf, Vbuf);

    dim3 ga(64, 16);
    attn_kernel<<<ga, 256, 0, stream>>>(Qbuf, Kbuf, Vbuf, Cbuf);

    dim3 gg(8, 64);
    out_gemm<<<gg, 256, 0, stream>>>(Cbuf, WoT, bo, out);
}